// Round 4
// baseline (494.479 us; speedup 1.0000x reference)
//
#include <hip/hip_runtime.h>
#include <math.h>

// Problem constants (from reference)
#define BS     32
#define LQ     300
#define DM     256
#define NH     8
#define CH     32      // DM / NH
#define SUMP   16
#define LV     8500    // 80*80+40*40+20*20+10*10
#define MROWS  (BS*LQ) // 9600
#define NW     384     // 256 off cols + 128 attn cols

// ---------------------------------------------------------------------------
// Kernel 1: P = query @ [w_off | w_attn] + [b_off | b_attn]
// M=9600, K=256, N=384 (cols [0,256)=off, [256,384)=attn), all f32.
// 64x64 tile, BK=32, 256 threads, 4x4 micro-tile per thread.
// ---------------------------------------------------------------------------
__global__ __launch_bounds__(256) void gemm_off_attn(
    const float* __restrict__ A,        // 9600 x 256
    const float* __restrict__ Boff,     // 256 x 256
    const float* __restrict__ Batt,     // 256 x 128
    const float* __restrict__ bias_off, // 256
    const float* __restrict__ bias_att, // 128
    float* __restrict__ C)              // 9600 x 384
{
    __shared__ float As[32][68];  // [k][m], pad 68 -> no power-of-2 stride
    __shared__ float Bs[32][68];  // [k][n]

    const int tid = threadIdx.x;
    const int m0  = blockIdx.x * 64;
    const int n0  = blockIdx.y * 64;

    const float* Bp; int ldb, nb0; const float* biasp;
    if (n0 < 256) { Bp = Boff; ldb = 256; nb0 = n0;       biasp = bias_off + n0; }
    else          { Bp = Batt; ldb = 128; nb0 = n0 - 256; biasp = bias_att + (n0 - 256); }

    const int tx = tid & 15;   // n quad
    const int ty = tid >> 4;   // m quad

    const int am = tid >> 3;         // A row within half-tile (0..31)
    const int ak = (tid & 7) * 4;    // A k offset (0..28)
    const int bk = tid >> 4;         // B k within half-tile (0..15)
    const int bn = (tid & 15) * 4;   // B n offset (0..60)

    float acc[4][4] = {};

    for (int k0 = 0; k0 < 256; k0 += 32) {
        #pragma unroll
        for (int pp = 0; pp < 2; ++pp) {
            const int m = pp * 32 + am;
            float4 a = *(const float4*)&A[(size_t)(m0 + m) * DM + k0 + ak];
            As[ak + 0][m] = a.x; As[ak + 1][m] = a.y;
            As[ak + 2][m] = a.z; As[ak + 3][m] = a.w;
            const int k = pp * 16 + bk;
            float4 b = *(const float4*)&Bp[(size_t)(k0 + k) * ldb + nb0 + bn];
            *(float4*)&Bs[k][bn] = b;
        }
        __syncthreads();
        #pragma unroll
        for (int k = 0; k < 32; ++k) {
            float4 av = *(const float4*)&As[k][ty * 4];
            float4 bv = *(const float4*)&Bs[k][tx * 4];
            float a[4] = {av.x, av.y, av.z, av.w};
            float b[4] = {bv.x, bv.y, bv.z, bv.w};
            #pragma unroll
            for (int i = 0; i < 4; ++i)
                #pragma unroll
                for (int j = 0; j < 4; ++j)
                    acc[i][j] = fmaf(a[i], b[j], acc[i][j]);
        }
        __syncthreads();
    }

    float4 bias = *(const float4*)&biasp[tx * 4];
    const float bb[4] = {bias.x, bias.y, bias.z, bias.w};
    #pragma unroll
    for (int i = 0; i < 4; ++i) {
        const int m = m0 + ty * 4 + i;
        float4 o;
        o.x = acc[i][0] + bb[0]; o.y = acc[i][1] + bb[1];
        o.z = acc[i][2] + bb[2]; o.w = acc[i][3] + bb[3];
        *(float4*)&C[(size_t)m * NW + n0 + tx * 4] = o;
    }
}

// ---------------------------------------------------------------------------
// Kernel 2: multiscale deformable attention sampling + weighted sum.
// One 32-lane group per (b,q,head); lane = channel. Each corner gather is a
// coalesced 128B read (channels of one head are contiguous in value).
// 8 groups (all heads of one (b,q)) share a 256-thread block -> P row and
// ref point broadcast from cache.
// ---------------------------------------------------------------------------
__global__ __launch_bounds__(256) void ms_deform(
    const float* __restrict__ P,     // 9600 x 384 (off | attn-logits)
    const float* __restrict__ ref,   // 9600 x 4
    const float* __restrict__ value, // 32 x 8500 x 256
    float* __restrict__ out)         // 9600 x 256
{
    const int lane = threadIdx.x & 31;
    const int gid  = blockIdx.x * 8 + (threadIdx.x >> 5); // (b*LQ+q)*8 + h
    const int h    = gid & 7;
    const int bq   = gid >> 3;
    const int b    = bq / LQ;

    const float4 r    = *(const float4*)&ref[(size_t)bq * 4];
    const float* prow = P + (size_t)bq * NW;

    // softmax weights over the 16 attention logits (unnormalized; 1/sum folded
    // into the final store)
    float w[SUMP];
    float mx = -1e30f;
    #pragma unroll
    for (int p = 0; p < SUMP; ++p) {
        w[p] = prow[256 + h * SUMP + p];
        mx = fmaxf(mx, w[p]);
    }
    float ssum = 0.f;
    #pragma unroll
    for (int p = 0; p < SUMP; ++p) { w[p] = __expf(w[p] - mx); ssum += w[p]; }
    const float inv = 1.f / ssum;

    const int Wd[4] = {80, 40, 20, 10};       // levels are square (H==W)
    const int St[4] = {0, 6400, 8000, 8400};  // level start offsets in value

    const float* vb0 = value + (size_t)b * LV * DM + h * CH + lane;
    float acc = 0.f;

    #pragma unroll
    for (int p = 0; p < SUMP; ++p) {
        const int lvl = p >> 2;
        const int W   = Wd[lvl];
        const float* vb = vb0 + (size_t)St[lvl] * DM;

        const float ox = prow[(h * SUMP + p) * 2 + 0];
        const float oy = prow[(h * SUMP + p) * 2 + 1];
        // loc = ref.xy + off * (1/4 points) * ref.wh * 0.5 ; x = loc.x*W - 0.5
        const float x = (r.x + ox * r.z * 0.125f) * (float)W - 0.5f;
        const float y = (r.y + oy * r.w * 0.125f) * (float)W - 0.5f;

        const float xf = floorf(x), yf = floorf(y);
        const float fx = x - xf,    fy = y - yf;
        const int   ix = (int)xf,   iy = (int)yf;

        const bool xv0 = (ix >= 0)     & (ix < W);
        const bool xv1 = (ix + 1 >= 0) & (ix + 1 < W);
        const bool yv0 = (iy >= 0)     & (iy < W);
        const bool yv1 = (iy + 1 >= 0) & (iy + 1 < W);

        const int cell = iy * W + ix;   // may be negative; loads are masked
        float v00 = 0.f, v10 = 0.f, v01 = 0.f, v11 = 0.f;
        if (xv0 & yv0) v00 = vb[(size_t)((cell)         ) * DM];
        if (xv1 & yv0) v10 = vb[(size_t)((cell + 1)     ) * DM];
        if (xv0 & yv1) v01 = vb[(size_t)((cell + W)     ) * DM];
        if (xv1 & yv1) v11 = vb[(size_t)((cell + W + 1) ) * DM];

        const float sv = (1.f - fx) * (1.f - fy) * v00 + fx * (1.f - fy) * v10
                       + (1.f - fx) * fy         * v01 + fx * fy         * v11;
        acc = fmaf(w[p], sv, acc);
    }

    out[(size_t)bq * DM + h * CH + lane] = acc * inv;
}

// ---------------------------------------------------------------------------
extern "C" void kernel_launch(void* const* d_in, const int* in_sizes, int n_in,
                              void* d_out, int out_size, void* d_ws, size_t ws_size,
                              hipStream_t stream) {
    const float* query  = (const float*)d_in[0];
    const float* refpts = (const float*)d_in[1];
    const float* value  = (const float*)d_in[2];
    const float* w_off  = (const float*)d_in[3];
    const float* b_off  = (const float*)d_in[4];
    const float* w_attn = (const float*)d_in[5];
    const float* b_attn = (const float*)d_in[6];
    float* out = (float*)d_out;
    float* P   = (float*)d_ws;   // 9600*384 f32 = 14.7 MB scratch

    dim3 gg(MROWS / 64, NW / 64);   // 150 x 6
    gemm_off_attn<<<gg, 256, 0, stream>>>(query, w_off, w_attn, b_off, b_attn, P);

    // 76,800 (b,q,h) tuples, 8 per 256-thread block
    ms_deform<<<(BS * LQ * NH) / 8, 256, 0, stream>>>(P, refpts, value, out);
}

// Round 6
// 418.264 us; speedup vs baseline: 1.1822x; 1.1822x over previous
//
#include <hip/hip_runtime.h>
#include <math.h>

// Problem constants (from reference)
#define BS     32
#define LQ     300
#define DM     256
#define NH     8
#define CH     32      // DM / NH
#define SUMP   16
#define LV     8500    // 80*80+40*40+20*20+10*10
#define MROWS  (BS*LQ) // 9600
#define NW     384     // 256 off cols + 128 attn cols

// ---------------------------------------------------------------------------
// Kernel 1: P = query @ [w_off | w_attn] + [b_off | b_attn]   (unchanged)
// ---------------------------------------------------------------------------
__global__ __launch_bounds__(256) void gemm_off_attn(
    const float* __restrict__ A,        // 9600 x 256
    const float* __restrict__ Boff,     // 256 x 256
    const float* __restrict__ Batt,     // 256 x 128
    const float* __restrict__ bias_off, // 256
    const float* __restrict__ bias_att, // 128
    float* __restrict__ C)              // 9600 x 384
{
    __shared__ float As[32][68];
    __shared__ float Bs[32][68];

    const int tid = threadIdx.x;
    const int m0  = blockIdx.x * 64;
    const int n0  = blockIdx.y * 64;

    const float* Bp; int ldb, nb0; const float* biasp;
    if (n0 < 256) { Bp = Boff; ldb = 256; nb0 = n0;       biasp = bias_off + n0; }
    else          { Bp = Batt; ldb = 128; nb0 = n0 - 256; biasp = bias_att + (n0 - 256); }

    const int tx = tid & 15;
    const int ty = tid >> 4;

    const int am = tid >> 3;
    const int ak = (tid & 7) * 4;
    const int bk = tid >> 4;
    const int bn = (tid & 15) * 4;

    float acc[4][4] = {};

    for (int k0 = 0; k0 < 256; k0 += 32) {
        #pragma unroll
        for (int pp = 0; pp < 2; ++pp) {
            const int m = pp * 32 + am;
            float4 a = *(const float4*)&A[(size_t)(m0 + m) * DM + k0 + ak];
            As[ak + 0][m] = a.x; As[ak + 1][m] = a.y;
            As[ak + 2][m] = a.z; As[ak + 3][m] = a.w;
            const int k = pp * 16 + bk;
            float4 b = *(const float4*)&Bp[(size_t)(k0 + k) * ldb + nb0 + bn];
            *(float4*)&Bs[k][bn] = b;
        }
        __syncthreads();
        #pragma unroll
        for (int k = 0; k < 32; ++k) {
            float4 av = *(const float4*)&As[k][ty * 4];
            float4 bv = *(const float4*)&Bs[k][tx * 4];
            float a[4] = {av.x, av.y, av.z, av.w};
            float b[4] = {bv.x, bv.y, bv.z, bv.w};
            #pragma unroll
            for (int i = 0; i < 4; ++i)
                #pragma unroll
                for (int j = 0; j < 4; ++j)
                    acc[i][j] = fmaf(a[i], b[j], acc[i][j]);
        }
        __syncthreads();
    }

    float4 bias = *(const float4*)&biasp[tx * 4];
    const float bb[4] = {bias.x, bias.y, bias.z, bias.w};
    #pragma unroll
    for (int i = 0; i < 4; ++i) {
        const int m = m0 + ty * 4 + i;
        float4 o;
        o.x = acc[i][0] + bb[0]; o.y = acc[i][1] + bb[1];
        o.z = acc[i][2] + bb[2]; o.w = acc[i][3] + bb[3];
        *(float4*)&C[(size_t)m * NW + n0 + tx * 4] = o;
    }
}

// ---------------------------------------------------------------------------
// Kernel 2 (rewritten for memory-level parallelism): one 64-lane wave per
// (b,q,head) tuple. Lane decomposition:
//   p2     = lane>>5      : which point of the current pair (2 points/iter)
//   corner = (lane>>3)&3  : bilinear corner (dx=corner&1, dy=corner>>1)
//   c4     = lane&7       : float4 chunk of the head's 32 channels
// Each of the 8 unrolled iterations issues ONE global_load_dwordx4 covering
// 2 points x 4 corners x 32 channels (64 lanes x 16B = 1KB). All 8 gathers
// are independent -> deep in-flight queue instead of 64 serial-ish loads.
// Final combine: shfl_xor over lane bits 3,4,5; store float4 from lanes 0-7.
// Borders: clamp address (stays in-buffer), zero the corner weight.
// ---------------------------------------------------------------------------
__global__ __launch_bounds__(256) void ms_deform(
    const float* __restrict__ P,     // 9600 x 384 (off | attn-logits)
    const float* __restrict__ ref,   // 9600 x 4
    const float* __restrict__ value, // 32 x 8500 x 256
    float* __restrict__ out)         // 9600 x 256
{
    const int tid  = threadIdx.x;
    const int lane = tid & 63;
    const int gid  = blockIdx.x * 4 + (tid >> 6);  // tuple id = bq*8 + h
    const int h    = gid & 7;
    const int bq   = gid >> 3;
    const int b    = bq / LQ;

    const int p2     = lane >> 5;
    const int corner = (lane >> 3) & 3;
    const int c4     = lane & 7;

    const float4 r    = *(const float4*)&ref[(size_t)bq * 4];
    const float* prow = P + (size_t)bq * NW;

    // offsets for this head: 32 floats = 8 uniform float4 loads.
    // o[k] = (p_{2k}.x, p_{2k}.y, p_{2k+1}.x, p_{2k+1}.y)
    float4 o[8];
    #pragma unroll
    for (int k = 0; k < 8; ++k) o[k] = *(const float4*)&prow[h * 32 + k * 4];

    // attn logits: 16 floats = 4 uniform float4 loads; softmax in-register.
    float4 L[4];
    #pragma unroll
    for (int k = 0; k < 4; ++k) L[k] = *(const float4*)&prow[256 + h * 16 + k * 4];

    float mx = -1e30f;
    #pragma unroll
    for (int k = 0; k < 4; ++k)
        mx = fmaxf(mx, fmaxf(fmaxf(L[k].x, L[k].y), fmaxf(L[k].z, L[k].w)));
    float ssum = 0.f;
    #pragma unroll
    for (int k = 0; k < 4; ++k) {
        L[k].x = __expf(L[k].x - mx); ssum += L[k].x;
        L[k].y = __expf(L[k].y - mx); ssum += L[k].y;
        L[k].z = __expf(L[k].z - mx); ssum += L[k].z;
        L[k].w = __expf(L[k].w - mx); ssum += L[k].w;
    }
    const float inv = 1.f / ssum;

    const float* vb0 = value + (size_t)b * LV * DM + h * CH + c4 * 4;

    const int Wd[4] = {80, 40, 20, 10};       // square levels
    const int St[4] = {0, 6400, 8000, 8400};  // level start offsets

    float4 acc = {0.f, 0.f, 0.f, 0.f};

    #pragma unroll
    for (int it = 0; it < 8; ++it) {
        const int lvl = it >> 1;              // points 2it,2it+1 share a level
        const int W   = Wd[lvl];
        const float fW = (float)W;

        const float ox = p2 ? o[it].z : o[it].x;
        const float oy = p2 ? o[it].w : o[it].y;

        // softmax weight for point p = 2it + p2 (compile-time components)
        float wA, wB;
        if ((it & 1) == 0) { wA = L[lvl].x; wB = L[lvl].y; }
        else               { wA = L[lvl].z; wB = L[lvl].w; }
        const float wp = p2 ? wB : wA;

        const float x = (r.x + ox * r.z * 0.125f) * fW - 0.5f;
        const float y = (r.y + oy * r.w * 0.125f) * fW - 0.5f;
        const float xf = floorf(x), yf = floorf(y);
        const float fx = x - xf,    fy = y - yf;

        const int ix = (int)xf + (corner & 1);
        const int iy = (int)yf + ((corner >> 1) & 1);
        const bool valid = (ix >= 0) & (ix < W) & (iy >= 0) & (iy < W);
        const int ixc = min(max(ix, 0), W - 1);
        const int iyc = min(max(iy, 0), W - 1);

        const float4 v = *(const float4*)&vb0[(size_t)(St[lvl] + iyc * W + ixc) * DM];

        const float wx = (corner & 1) ? fx : 1.f - fx;
        const float wy = (corner & 2) ? fy : 1.f - fy;
        const float s  = wp * wx * wy * (valid ? 1.f : 0.f);

        acc.x = fmaf(s, v.x, acc.x);
        acc.y = fmaf(s, v.y, acc.y);
        acc.z = fmaf(s, v.z, acc.z);
        acc.w = fmaf(s, v.w, acc.w);
    }

    // reduce across corner (bits 3,4) and point-pair (bit 5)
    #pragma unroll
    for (int m = 8; m <= 32; m <<= 1) {
        acc.x += __shfl_xor(acc.x, m, 64);
        acc.y += __shfl_xor(acc.y, m, 64);
        acc.z += __shfl_xor(acc.z, m, 64);
        acc.w += __shfl_xor(acc.w, m, 64);
    }

    if (lane < 8) {
        float4 ov;
        ov.x = acc.x * inv; ov.y = acc.y * inv;
        ov.z = acc.z * inv; ov.w = acc.w * inv;
        *(float4*)&out[(size_t)bq * DM + h * CH + c4 * 4] = ov;
    }
}

// ---------------------------------------------------------------------------
extern "C" void kernel_launch(void* const* d_in, const int* in_sizes, int n_in,
                              void* d_out, int out_size, void* d_ws, size_t ws_size,
                              hipStream_t stream) {
    const float* query  = (const float*)d_in[0];
    const float* refpts = (const float*)d_in[1];
    const float* value  = (const float*)d_in[2];
    const float* w_off  = (const float*)d_in[3];
    const float* b_off  = (const float*)d_in[4];
    const float* w_attn = (const float*)d_in[5];
    const float* b_attn = (const float*)d_in[6];
    float* out = (float*)d_out;
    float* P   = (float*)d_ws;   // 9600*384 f32 = 14.7 MB scratch

    dim3 gg(MROWS / 64, NW / 64);   // 150 x 6
    gemm_off_attn<<<gg, 256, 0, stream>>>(query, w_off, w_attn, b_off, b_attn, P);

    // one wave per (b,q,h) tuple; 4 waves (tuples) per 256-thread block
    ms_deform<<<(BS * LQ * NH) / 4, 256, 0, stream>>>(P, refpts, value, out);
}

// Round 7
// 396.346 us; speedup vs baseline: 1.2476x; 1.0553x over previous
//
#include <hip/hip_runtime.h>
#include <math.h>

// Problem constants (from reference)
#define BS     32
#define LQ     300
#define DM     256
#define NH     8
#define CH     32      // DM / NH
#define SUMP   16
#define LV     8500    // 80*80+40*40+20*20+10*10
#define MROWS  (BS*LQ) // 9600
#define NW     384     // 256 off cols + 128 attn cols

// ---------------------------------------------------------------------------
// Kernel 1: P = query @ [w_off | w_attn] + [b_off | b_attn]   (unchanged)
// ---------------------------------------------------------------------------
__global__ __launch_bounds__(256) void gemm_off_attn(
    const float* __restrict__ A,        // 9600 x 256
    const float* __restrict__ Boff,     // 256 x 256
    const float* __restrict__ Batt,     // 256 x 128
    const float* __restrict__ bias_off, // 256
    const float* __restrict__ bias_att, // 128
    float* __restrict__ C)              // 9600 x 384
{
    __shared__ float As[32][68];
    __shared__ float Bs[32][68];

    const int tid = threadIdx.x;
    const int m0  = blockIdx.x * 64;
    const int n0  = blockIdx.y * 64;

    const float* Bp; int ldb, nb0; const float* biasp;
    if (n0 < 256) { Bp = Boff; ldb = 256; nb0 = n0;       biasp = bias_off + n0; }
    else          { Bp = Batt; ldb = 128; nb0 = n0 - 256; biasp = bias_att + (n0 - 256); }

    const int tx = tid & 15;
    const int ty = tid >> 4;

    const int am = tid >> 3;
    const int ak = (tid & 7) * 4;
    const int bk = tid >> 4;
    const int bn = (tid & 15) * 4;

    float acc[4][4] = {};

    for (int k0 = 0; k0 < 256; k0 += 32) {
        #pragma unroll
        for (int pp = 0; pp < 2; ++pp) {
            const int m = pp * 32 + am;
            float4 a = *(const float4*)&A[(size_t)(m0 + m) * DM + k0 + ak];
            As[ak + 0][m] = a.x; As[ak + 1][m] = a.y;
            As[ak + 2][m] = a.z; As[ak + 3][m] = a.w;
            const int k = pp * 16 + bk;
            float4 b = *(const float4*)&Bp[(size_t)(k0 + k) * ldb + nb0 + bn];
            *(float4*)&Bs[k][bn] = b;
        }
        __syncthreads();
        #pragma unroll
        for (int k = 0; k < 32; ++k) {
            float4 av = *(const float4*)&As[k][ty * 4];
            float4 bv = *(const float4*)&Bs[k][tx * 4];
            float a[4] = {av.x, av.y, av.z, av.w};
            float b[4] = {bv.x, bv.y, bv.z, bv.w};
            #pragma unroll
            for (int i = 0; i < 4; ++i)
                #pragma unroll
                for (int j = 0; j < 4; ++j)
                    acc[i][j] = fmaf(a[i], b[j], acc[i][j]);
        }
        __syncthreads();
    }

    float4 bias = *(const float4*)&biasp[tx * 4];
    const float bb[4] = {bias.x, bias.y, bias.z, bias.w};
    #pragma unroll
    for (int i = 0; i < 4; ++i) {
        const int m = m0 + ty * 4 + i;
        float4 o;
        o.x = acc[i][0] + bb[0]; o.y = acc[i][1] + bb[1];
        o.z = acc[i][2] + bb[2]; o.w = acc[i][3] + bb[3];
        *(float4*)&C[(size_t)m * NW + n0 + tx * 4] = o;
    }
}

// ---------------------------------------------------------------------------
// Kernel 2: block-per-(b,q) cooperative two-phase sampler.
// Phase A: coop-load P row (384f) + ref into LDS; 128 threads compute softmax
//   (16-lane shfl groups) and per-(h,p) premultiplied/masked/normalized corner
//   weights + base pixel index into LDS. Location math computed ONCE.
// Phase B: wave w handles heads {2w, 2w+1}: 16 independent 1KB gathers
//   (global_load_dwordx4 x 64 lanes), weights from LDS, shfl_xor reduce,
//   float4 stores from lanes 0-7. No uniform VMEM in phase B.
// ---------------------------------------------------------------------------
__global__ __launch_bounds__(256) void ms_deform(
    const float* __restrict__ P,     // 9600 x 384 (off | attn-logits)
    const float* __restrict__ ref,   // 9600 x 4
    const float* __restrict__ value, // 32 x 8500 x 256
    float* __restrict__ out)         // 9600 x 256
{
    __shared__ float  s_P[384];
    __shared__ float4 s_ref;
    __shared__ float  s_data[128][8];  // w00,w10,w01,w11, ix0(bits), iy0(bits)

    // XCD-chunk swizzle: 9600 blocks, 8 XCDs, 1200 contiguous bq per XCD
    const int bid = blockIdx.x;
    const int bq  = (bid & 7) * 1200 + (bid >> 3);
    const int tid = threadIdx.x;
    const int b   = bq / LQ;

    if (tid < 96) ((float4*)s_P)[tid] = ((const float4*)(P + (size_t)bq * NW))[tid];
    if (tid == 96) s_ref = *(const float4*)&ref[(size_t)bq * 4];
    __syncthreads();

    const int Wd[4] = {80, 40, 20, 10};
    const int St[4] = {0, 6400, 8000, 8400};

    if (tid < 128) {
        const int h = tid >> 4, p = tid & 15, lvl = p >> 2;
        const float4 r = s_ref;
        const float lg = s_P[256 + h * 16 + p];
        // softmax across the 16-lane point group
        float m = lg;
        #pragma unroll
        for (int mk = 1; mk <= 8; mk <<= 1) m = fmaxf(m, __shfl_xor(m, mk, 64));
        const float e = __expf(lg - m);
        float s = e;
        #pragma unroll
        for (int mk = 1; mk <= 8; mk <<= 1) s += __shfl_xor(s, mk, 64);
        const float wn = e / s;   // normalized softmax weight

        const float ox = s_P[h * 32 + p * 2], oy = s_P[h * 32 + p * 2 + 1];
        const int   W  = Wd[lvl];
        const float fW = (float)W;
        const float x  = (r.x + ox * r.z * 0.125f) * fW - 0.5f;
        const float y  = (r.y + oy * r.w * 0.125f) * fW - 0.5f;
        const float xf = floorf(x), yf = floorf(y);
        const float fx = x - xf,    fy = y - yf;
        const int ix0 = (int)xf, iy0 = (int)yf;
        const float xv0 = (ix0 >= 0     && ix0 < W)     ? 1.f : 0.f;
        const float xv1 = (ix0 + 1 >= 0 && ix0 + 1 < W) ? 1.f : 0.f;
        const float yv0 = (iy0 >= 0     && iy0 < W)     ? 1.f : 0.f;
        const float yv1 = (iy0 + 1 >= 0 && iy0 + 1 < W) ? 1.f : 0.f;
        s_data[tid][0] = wn * (1.f - fx) * (1.f - fy) * xv0 * yv0;
        s_data[tid][1] = wn * fx         * (1.f - fy) * xv1 * yv0;
        s_data[tid][2] = wn * (1.f - fx) * fy         * xv0 * yv1;
        s_data[tid][3] = wn * fx         * fy         * xv1 * yv1;
        s_data[tid][4] = __int_as_float(ix0);
        s_data[tid][5] = __int_as_float(iy0);
    }
    __syncthreads();

    const int w    = tid >> 6;   // wave 0..3 -> heads {2w, 2w+1}
    const int lane = tid & 63;
    const int grp  = lane >> 3;  // gather slot within instruction
    const int c4   = lane & 7;   // float4 chunk of the 32 head channels

    const float* vbase = value + (size_t)b * LV * DM + c4 * 4;

    float4 accA = {0.f, 0.f, 0.f, 0.f};
    float4 accB = {0.f, 0.f, 0.f, 0.f};

    #pragma unroll
    for (int i = 0; i < 16; ++i) {
        const int g      = w * 128 + i * 8 + grp;  // 0..511 = (h,p,corner)
        const int corner = g & 3;
        const int hp     = g >> 2;                 // h*16 + p
        const int p      = hp & 15;
        const int h      = g >> 6;                 // 2w (+1 for i>=8)
        const int lvl    = p >> 2;
        const int W      = Wd[lvl];

        const float wc = s_data[hp][corner];
        int ix = __float_as_int(s_data[hp][4]) + (corner & 1);
        int iy = __float_as_int(s_data[hp][5]) + (corner >> 1);
        ix = min(max(ix, 0), W - 1);
        iy = min(max(iy, 0), W - 1);
        const size_t flat = (size_t)(St[lvl] + iy * W + ix);

        const float4 v = *(const float4*)&vbase[flat * DM + h * CH];

        if (i < 8) {
            accA.x = fmaf(wc, v.x, accA.x); accA.y = fmaf(wc, v.y, accA.y);
            accA.z = fmaf(wc, v.z, accA.z); accA.w = fmaf(wc, v.w, accA.w);
        } else {
            accB.x = fmaf(wc, v.x, accB.x); accB.y = fmaf(wc, v.y, accB.y);
            accB.z = fmaf(wc, v.z, accB.z); accB.w = fmaf(wc, v.w, accB.w);
        }
    }

    // fold the 8 gather slots together (lane bits 3,4,5)
    #pragma unroll
    for (int mk = 8; mk <= 32; mk <<= 1) {
        accA.x += __shfl_xor(accA.x, mk, 64); accA.y += __shfl_xor(accA.y, mk, 64);
        accA.z += __shfl_xor(accA.z, mk, 64); accA.w += __shfl_xor(accA.w, mk, 64);
        accB.x += __shfl_xor(accB.x, mk, 64); accB.y += __shfl_xor(accB.y, mk, 64);
        accB.z += __shfl_xor(accB.z, mk, 64); accB.w += __shfl_xor(accB.w, mk, 64);
    }

    if (lane < 8) {
        *(float4*)&out[(size_t)bq * DM + (2 * w)     * CH + c4 * 4] = accA;
        *(float4*)&out[(size_t)bq * DM + (2 * w + 1) * CH + c4 * 4] = accB;
    }
}

// ---------------------------------------------------------------------------
extern "C" void kernel_launch(void* const* d_in, const int* in_sizes, int n_in,
                              void* d_out, int out_size, void* d_ws, size_t ws_size,
                              hipStream_t stream) {
    const float* query  = (const float*)d_in[0];
    const float* refpts = (const float*)d_in[1];
    const float* value  = (const float*)d_in[2];
    const float* w_off  = (const float*)d_in[3];
    const float* b_off  = (const float*)d_in[4];
    const float* w_attn = (const float*)d_in[5];
    const float* b_attn = (const float*)d_in[6];
    float* out = (float*)d_out;
    float* P   = (float*)d_ws;   // 9600*384 f32 = 14.7 MB scratch

    dim3 gg(MROWS / 64, NW / 64);   // 150 x 6
    gemm_off_attn<<<gg, 256, 0, stream>>>(query, w_off, w_attn, b_off, b_attn, P);

    // one block per (b,q); 8 heads handled by 4 waves (2 heads/wave)
    ms_deform<<<MROWS, 256, 0, stream>>>(P, refpts, value, out);
}

// Round 10
// 395.742 us; speedup vs baseline: 1.2495x; 1.0015x over previous
//
#include <hip/hip_runtime.h>
#include <math.h>

// Problem constants (from reference)
#define BS     32
#define LQ     300
#define DM     256
#define NH     8
#define CH     32      // DM / NH
#define SUMP   16
#define LV     8500    // 80*80+40*40+20*20+10*10
#define MROWS  (BS*LQ) // 9600
#define NW     384     // 256 off cols + 128 attn cols

// ---------------------------------------------------------------------------
// Kernel 1: P = query @ [w_off | w_attn] + [b_off | b_attn]   (unchanged)
// ---------------------------------------------------------------------------
__global__ __launch_bounds__(256) void gemm_off_attn(
    const float* __restrict__ A,        // 9600 x 256
    const float* __restrict__ Boff,     // 256 x 256
    const float* __restrict__ Batt,     // 256 x 128
    const float* __restrict__ bias_off, // 256
    const float* __restrict__ bias_att, // 128
    float* __restrict__ C)              // 9600 x 384
{
    __shared__ float As[32][68];
    __shared__ float Bs[32][68];

    const int tid = threadIdx.x;
    const int m0  = blockIdx.x * 64;
    const int n0  = blockIdx.y * 64;

    const float* Bp; int ldb, nb0; const float* biasp;
    if (n0 < 256) { Bp = Boff; ldb = 256; nb0 = n0;       biasp = bias_off + n0; }
    else          { Bp = Batt; ldb = 128; nb0 = n0 - 256; biasp = bias_att + (n0 - 256); }

    const int tx = tid & 15;
    const int ty = tid >> 4;

    const int am = tid >> 3;
    const int ak = (tid & 7) * 4;
    const int bk = tid >> 4;
    const int bn = (tid & 15) * 4;

    float acc[4][4] = {};

    for (int k0 = 0; k0 < 256; k0 += 32) {
        #pragma unroll
        for (int pp = 0; pp < 2; ++pp) {
            const int m = pp * 32 + am;
            float4 a = *(const float4*)&A[(size_t)(m0 + m) * DM + k0 + ak];
            As[ak + 0][m] = a.x; As[ak + 1][m] = a.y;
            As[ak + 2][m] = a.z; As[ak + 3][m] = a.w;
            const int k = pp * 16 + bk;
            float4 b = *(const float4*)&Bp[(size_t)(k0 + k) * ldb + nb0 + bn];
            *(float4*)&Bs[k][bn] = b;
        }
        __syncthreads();
        #pragma unroll
        for (int k = 0; k < 32; ++k) {
            float4 av = *(const float4*)&As[k][ty * 4];
            float4 bv = *(const float4*)&Bs[k][tx * 4];
            float a[4] = {av.x, av.y, av.z, av.w};
            float b[4] = {bv.x, bv.y, bv.z, bv.w};
            #pragma unroll
            for (int i = 0; i < 4; ++i)
                #pragma unroll
                for (int j = 0; j < 4; ++j)
                    acc[i][j] = fmaf(a[i], b[j], acc[i][j]);
        }
        __syncthreads();
    }

    float4 bias = *(const float4*)&biasp[tx * 4];
    const float bb[4] = {bias.x, bias.y, bias.z, bias.w};
    #pragma unroll
    for (int i = 0; i < 4; ++i) {
        const int m = m0 + ty * 4 + i;
        float4 o;
        o.x = acc[i][0] + bb[0]; o.y = acc[i][1] + bb[1];
        o.z = acc[i][2] + bb[2]; o.w = acc[i][3] + bb[3];
        *(float4*)&C[(size_t)m * NW + n0 + tx * 4] = o;
    }
}

// ---------------------------------------------------------------------------
// Kernel 2: block-per-(b,q) cooperative two-phase sampler.
// Phase A: coop-load P row + ref into LDS; 128 threads compute softmax and,
//   per (h,p): 4 premultiplied/masked/normalized corner weights AND 4 fully
//   resolved flat element offsets ((St + iy*W + ix)*DM + h*CH), packed as
//   (w, off) float2 pairs. ALL address/weight math happens once, here.
// Phase B: wave w covers heads {2w,2w+1} = 128 (h,p,corner) slots in 16
//   iterations; per iter: 1 ds_read_b64 + 1 global_load_dwordx4 + 4 FMA.
//   No index math in the loop. shfl_xor reduce, float4 store from lanes 0-7.
// ---------------------------------------------------------------------------
__global__ __launch_bounds__(256) void ms_deform(
    const float* __restrict__ P,     // 9600 x 384 (off | attn-logits)
    const float* __restrict__ ref,   // 9600 x 4
    const float* __restrict__ value, // 32 x 8500 x 256
    float* __restrict__ out)         // 9600 x 256
{
    __shared__ float  s_P[384];
    __shared__ float4 s_ref;
    // [hp][2*c] = weight, [hp][2*c+1] = flat offset (int bits); stride 10
    // words -> <=4-way write conflict (once per block), 8B-aligned b64 reads.
    __shared__ float  s_data[128][10];

    // XCD-chunk swizzle: 9600 blocks, 8 XCDs, 1200 contiguous bq per XCD
    const int bid = blockIdx.x;
    const int bq  = (bid & 7) * 1200 + (bid >> 3);
    const int tid = threadIdx.x;
    const int b   = bq / LQ;

    if (tid < 96) ((float4*)s_P)[tid] = ((const float4*)(P + (size_t)bq * NW))[tid];
    if (tid == 96) s_ref = *(const float4*)&ref[(size_t)bq * 4];
    __syncthreads();

    const int Wd[4] = {80, 40, 20, 10};
    const int St[4] = {0, 6400, 8000, 8400};

    if (tid < 128) {
        const int h = tid >> 4, p = tid & 15, lvl = p >> 2;
        const float4 r = s_ref;
        const float lg = s_P[256 + h * 16 + p];
        // softmax across the 16-lane point group
        float m = lg;
        #pragma unroll
        for (int mk = 1; mk <= 8; mk <<= 1) m = fmaxf(m, __shfl_xor(m, mk, 64));
        const float e = __expf(lg - m);
        float s = e;
        #pragma unroll
        for (int mk = 1; mk <= 8; mk <<= 1) s += __shfl_xor(s, mk, 64);
        const float wn = e / s;   // normalized softmax weight

        const float ox = s_P[h * 32 + p * 2], oy = s_P[h * 32 + p * 2 + 1];
        const int   W  = Wd[lvl];
        const float fW = (float)W;
        const float x  = (r.x + ox * r.z * 0.125f) * fW - 0.5f;
        const float y  = (r.y + oy * r.w * 0.125f) * fW - 0.5f;
        const float xf = floorf(x), yf = floorf(y);
        const float fx = x - xf,    fy = y - yf;
        const int ix0 = (int)xf, iy0 = (int)yf;
        const float xv0 = (ix0 >= 0     && ix0 < W)     ? 1.f : 0.f;
        const float xv1 = (ix0 + 1 < W)                 ? 1.f : 0.f;
        const float yv0 = (iy0 >= 0     && iy0 < W)     ? 1.f : 0.f;
        const float yv1 = (iy0 + 1 < W)                 ? 1.f : 0.f;
        const float xv1f = (ix0 + 1 >= 0) ? xv1 : 0.f;
        const float yv1f = (iy0 + 1 >= 0) ? yv1 : 0.f;

        const int ix0c = min(max(ix0, 0), W - 1);
        const int ix1c = min(max(ix0 + 1, 0), W - 1);
        const int iy0c = min(max(iy0, 0), W - 1);
        const int iy1c = min(max(iy0 + 1, 0), W - 1);
        const int base = St[lvl];
        const int hch  = h * CH;

        s_data[tid][0] = wn * (1.f - fx) * (1.f - fy) * xv0  * yv0;
        s_data[tid][1] = __int_as_float((base + iy0c * W + ix0c) * DM + hch);
        s_data[tid][2] = wn * fx         * (1.f - fy) * xv1f * yv0;
        s_data[tid][3] = __int_as_float((base + iy0c * W + ix1c) * DM + hch);
        s_data[tid][4] = wn * (1.f - fx) * fy         * xv0  * yv1f;
        s_data[tid][5] = __int_as_float((base + iy1c * W + ix0c) * DM + hch);
        s_data[tid][6] = wn * fx         * fy         * xv1f * yv1f;
        s_data[tid][7] = __int_as_float((base + iy1c * W + ix1c) * DM + hch);
    }
    __syncthreads();

    const int w    = tid >> 6;   // wave 0..3 -> heads {2w, 2w+1}
    const int lane = tid & 63;
    const int grp  = lane >> 3;  // gather slot within instruction (0..7)
    const int c4   = lane & 7;   // float4 chunk of the 32 head channels

    // slot g = w*128 + i*8 + grp ; hp = g>>2 = (w*32 + (grp>>2)) + 2*i ;
    // corner = grp&3 (loop-invariant)
    const int hp0     = w * 32 + (grp >> 2);
    const int corner2 = (grp & 3) * 2;

    const float* vbase = value + (size_t)b * LV * DM + c4 * 4;

    float4 accA = {0.f, 0.f, 0.f, 0.f};
    float4 accB = {0.f, 0.f, 0.f, 0.f};

    #pragma unroll
    for (int i = 0; i < 16; ++i) {
        const float2 wo = *(const float2*)&s_data[hp0 + 2 * i][corner2];
        const float4 v  = *(const float4*)&vbase[(size_t)__float_as_int(wo.y)];
        if (i < 8) {
            accA.x = fmaf(wo.x, v.x, accA.x); accA.y = fmaf(wo.x, v.y, accA.y);
            accA.z = fmaf(wo.x, v.z, accA.z); accA.w = fmaf(wo.x, v.w, accA.w);
        } else {
            accB.x = fmaf(wo.x, v.x, accB.x); accB.y = fmaf(wo.x, v.y, accB.y);
            accB.z = fmaf(wo.x, v.z, accB.z); accB.w = fmaf(wo.x, v.w, accB.w);
        }
    }

    // fold the 8 gather slots together (lane bits 3,4,5)
    #pragma unroll
    for (int mk = 8; mk <= 32; mk <<= 1) {
        accA.x += __shfl_xor(accA.x, mk, 64); accA.y += __shfl_xor(accA.y, mk, 64);
        accA.z += __shfl_xor(accA.z, mk, 64); accA.w += __shfl_xor(accA.w, mk, 64);
        accB.x += __shfl_xor(accB.x, mk, 64); accB.y += __shfl_xor(accB.y, mk, 64);
        accB.z += __shfl_xor(accB.z, mk, 64); accB.w += __shfl_xor(accB.w, mk, 64);
    }

    if (lane < 8) {
        *(float4*)&out[(size_t)bq * DM + (2 * w)     * CH + c4 * 4] = accA;
        *(float4*)&out[(size_t)bq * DM + (2 * w + 1) * CH + c4 * 4] = accB;
    }
}

// ---------------------------------------------------------------------------
extern "C" void kernel_launch(void* const* d_in, const int* in_sizes, int n_in,
                              void* d_out, int out_size, void* d_ws, size_t ws_size,
                              hipStream_t stream) {
    const float* query  = (const float*)d_in[0];
    const float* refpts = (const float*)d_in[1];
    const float* value  = (const float*)d_in[2];
    const float* w_off  = (const float*)d_in[3];
    const float* b_off  = (const float*)d_in[4];
    const float* w_attn = (const float*)d_in[5];
    const float* b_attn = (const float*)d_in[6];
    float* out = (float*)d_out;
    float* P   = (float*)d_ws;   // 9600*384 f32 = 14.7 MB scratch

    dim3 gg(MROWS / 64, NW / 64);   // 150 x 6
    gemm_off_attn<<<gg, 256, 0, stream>>>(query, w_off, w_attn, b_off, b_attn, P);

    // one block per (b,q); 8 heads handled by 4 waves (2 heads/wave)
    ms_deform<<<MROWS, 256, 0, stream>>>(P, refpts, value, out);
}